// Round 2
// baseline (3425.146 us; speedup 1.0000x reference)
//
#include <hip/hip_runtime.h>
#include <math.h>

#define NH 8
#define HD 64
#define CC 512
#define NPOS 3136
#define BB 16
#define MM (BB*NPOS)   // 50176
#define KD 512
#define SPLIT 4
#define CHUNK (NPOS/SPLIT) // 784

// ---------------- prep: scale_inv, power ----------------
__global__ __launch_bounds__(512) void prep_kernel(const float* __restrict__ scale_p,
                                                   const float* __restrict__ power_p,
                                                   float* __restrict__ scinv,
                                                   float* __restrict__ pwr)
{
  int t = threadIdx.x;
  if (t < CC) {
    float sp = scale_p[t];
    scinv[t] = 1.f / log1pf(expf(sp));          // 1/softplus
    float pp = power_p[t];
    pwr[t] = 1.f + 4.f / (1.f + expf(-pp));     // 1 + ALPHA*sigmoid
  }
}

// ---------------- fp32 GEMM, 128x128x8 tile, 8x8/thread ----------------
#define BM 128
#define BN 128
#define BK 8

// mode 0: A natural; out0=q head-major (scaled), out1=g natural (d_out)
// mode 1: A natural; out0=k head-major (pos_enc+scale), out1=v head-major
// mode 2: A head-major (b,h,n,d); out0 = d_out natural, bias added
__global__ __launch_bounds__(256) void gemm_kernel(
    const float* __restrict__ A, const float* __restrict__ Bm,
    int Nc, int mode,
    const float* __restrict__ scinv, const float* __restrict__ pos_enc,
    const float* __restrict__ bias,
    float* __restrict__ out0, float* __restrict__ out1)
{
  __shared__ float As[BK][BM+4];
  __shared__ float Bs[BK][BN+4];
  const int t  = threadIdx.x;
  const int n0 = blockIdx.x * BN;
  const int m0 = blockIdx.y * BM;
  const int tx = t & 15, ty = t >> 4;
  const int am = t >> 1, akg = (t & 1) << 2;
  const int bk = t >> 5, bn = (t & 31) << 2;
  const int mrow = m0 + am;
  const int abb = mrow / NPOS, ann = mrow % NPOS;  // for head-major A (mode 2)
  const float* Bp = Bm + (size_t)bk * Nc + n0 + bn;

  // A-tile address for k-offset k0 (loads 4 consecutive floats at k0+akg)
  #define A_ADDR(k0r) ((mode != 2) \
      ? (A + (size_t)mrow * KD + (k0r) + akg) \
      : (A + ((((size_t)(abb*NH + (((k0r)+akg) >> 6)))*NPOS + ann) << 6) + (((k0r)+akg) & 63)))

  float acc[8][8];
  #pragma unroll
  for (int i = 0; i < 8; i++)
    #pragma unroll
    for (int j = 0; j < 8; j++) acc[i][j] = 0.f;

  float4 av = *(const float4*)A_ADDR(0);
  float4 bv = *(const float4*)Bp;

  for (int k0 = 0; k0 < KD; k0 += BK) {
    As[akg+0][am] = av.x; As[akg+1][am] = av.y;
    As[akg+2][am] = av.z; As[akg+3][am] = av.w;
    *(float4*)&Bs[bk][bn] = bv;
    __syncthreads();
    if (k0 + BK < KD) {
      av = *(const float4*)A_ADDR(k0 + BK);
      bv = *(const float4*)(Bp + (size_t)(k0 + BK) * Nc);
    }
    #pragma unroll
    for (int kk = 0; kk < BK; kk++) {
      float4 a0 = *(const float4*)&As[kk][ty*8];
      float4 a1 = *(const float4*)&As[kk][ty*8+4];
      float4 b0 = *(const float4*)&Bs[kk][tx*4];
      float4 b1 = *(const float4*)&Bs[kk][64 + tx*4];
      float ar[8] = {a0.x,a0.y,a0.z,a0.w,a1.x,a1.y,a1.z,a1.w};
      float br[8] = {b0.x,b0.y,b0.z,b0.w,b1.x,b1.y,b1.z,b1.w};
      #pragma unroll
      for (int i = 0; i < 8; i++)
        #pragma unroll
        for (int j = 0; j < 8; j++)
          acc[i][j] = fmaf(ar[i], br[j], acc[i][j]);
    }
    __syncthreads();
  }
  #undef A_ADDR

  #pragma unroll
  for (int i = 0; i < 8; i++) {
    const int m  = m0 + ty*8 + i;
    const int bb = m / NPOS;
    const int nn = m % NPOS;
    #pragma unroll
    for (int j = 0; j < 8; j++) {
      const int col = n0 + ((j < 4) ? (tx*4 + j) : (64 + tx*4 + (j-4)));
      const float val = acc[i][j];
      if (mode == 2) {
        out0[(size_t)m*CC + col] = val + bias[col];
      } else if (col < CC) {
        const int h = col >> 6, d = col & 63;
        float sv;
        if (mode == 0) sv = val * scinv[col];
        else           sv = (val + pos_enc[(size_t)nn*CC + col]) * scinv[col];
        out0[(((size_t)(bb*NH + h)*NPOS + nn) << 6) + d] = sv;
      } else {
        const int c2 = col - CC;
        if (mode == 0) {
          out1[(size_t)m*CC + c2] = val;                      // g natural (d_out)
        } else {
          const int h = c2 >> 6, d = c2 & 63;                 // v head-major
          out1[(((size_t)(bb*NH + h)*NPOS + nn) << 6) + d] = val;
        }
      }
    }
  }
}

// ---------------- kf outer-product reduction (partials) ----------------
__global__ __launch_bounds__(256) void reduce_kv_kernel(
    const float* __restrict__ ws_k, const float* __restrict__ ws_v,
    const float* __restrict__ pwr,
    float* __restrict__ pkv, float* __restrict__ pkm)
{
  const int bh = blockIdx.x / SPLIT, s = blockIdx.x % SPLIT;
  const int h = bh & 7;
  const int t = threadIdx.x;
  __shared__ float kf_s[128];
  __shared__ float v_s[64];
  const int d = t >> 1, eh = (t & 1) << 5;
  const float p = (t < 64) ? pwr[h*64 + t] : 0.f;
  float acc[32];
  #pragma unroll
  for (int j = 0; j < 32; j++) acc[j] = 0.f;
  float accm = 0.f;
  const int n0 = s * CHUNK;
  for (int i = 0; i < CHUNK; i++) {
    const int nn = n0 + i;
    if (t < 64) {
      float kk = ws_k[(((size_t)bh*NPOS + nn) << 6) + t];
      kf_s[t]      = (kk > 0.f) ? expf(p * logf( kk)) : 0.f;
      kf_s[t + 64] = (kk < 0.f) ? expf(p * logf(-kk)) : 0.f;
    } else if (t < 128) {
      v_s[t - 64] = ws_v[(((size_t)bh*NPOS + nn) << 6) + (t - 64)];
    }
    __syncthreads();
    const float kfd = kf_s[d];
    accm += kfd;
    #pragma unroll
    for (int j4 = 0; j4 < 8; j4++) {
      float4 vv = *(const float4*)&v_s[eh + j4*4];
      acc[j4*4+0] = fmaf(kfd, vv.x, acc[j4*4+0]);
      acc[j4*4+1] = fmaf(kfd, vv.y, acc[j4*4+1]);
      acc[j4*4+2] = fmaf(kfd, vv.z, acc[j4*4+2]);
      acc[j4*4+3] = fmaf(kfd, vv.w, acc[j4*4+3]);
    }
    __syncthreads();
  }
  float* outp = pkv + ((size_t)(s*128 + bh) << 13) + (d << 6) + eh;
  #pragma unroll
  for (int j4 = 0; j4 < 8; j4++)
    *(float4*)(outp + j4*4) = make_float4(acc[j4*4+0], acc[j4*4+1], acc[j4*4+2], acc[j4*4+3]);
  if (!(t & 1)) pkm[((s*128 + bh) << 7) + d] = accm;
}

__global__ __launch_bounds__(256) void reduce_final_kernel(
    const float* __restrict__ pkv, const float* __restrict__ pkm,
    float* __restrict__ kvf, float* __restrict__ km)
{
  const int bh = blockIdx.x;
  const int t = threadIdx.x;
  const float inv_n = 1.f / (float)NPOS;
  for (int i = t; i < 8192; i += 256) {
    float ssum = 0.f;
    #pragma unroll
    for (int s = 0; s < SPLIT; s++) ssum += pkv[((size_t)(s*128 + bh) << 13) + i];
    kvf[((size_t)bh << 13) + i] = ssum * inv_n;
  }
  if (t < 128) {
    float sm = 0.f;
    #pragma unroll
    for (int s = 0; s < SPLIT; s++) sm += pkm[((s*128 + bh) << 7) + t];
    km[(bh << 7) + t] = sm * inv_n;
  }
}

// ---------------- linear attention apply (in-place q -> xo, head-major) ----
__global__ __launch_bounds__(256) void attn_kernel(
    float* qxo, const float* __restrict__ kvf,
    const float* __restrict__ km, const float* __restrict__ pwr)
{
  __shared__ float kvf_s[8192];
  __shared__ float km_s[128];
  const int t = threadIdx.x;
  const int bh = blockIdx.y;
  const int h = bh & 7;
  const float4* src = (const float4*)(kvf + ((size_t)bh << 13));
  #pragma unroll
  for (int i = 0; i < 8; i++) ((float4*)kvf_s)[t + 256*i] = src[t + 256*i];
  if (t < 128) km_s[t] = km[(bh << 7) + t];
  __syncthreads();

  const int wid = t >> 6, l = t & 63;
  const float p = pwr[h*64 + l];
  const float km0 = km_s[l], km1 = km_s[64 + l];
  const int base1 = ((l < 32) ? 0 : 4096) + l;
  const int base2 = ((l < 32) ? 4096 : 0) + l;

  for (int i = 0; i < 16; i++) {
    const int nn = blockIdx.x*64 + wid*16 + i;
    const size_t addr = (((size_t)bh*NPOS + nn) << 6) + l;
    const float qv = qxo[addr];
    const float qp = (qv > 0.f) ? expf(p * logf( qv)) : 0.f;
    const float qn = (qv < 0.f) ? expf(p * logf(-qv)) : 0.f;
    float ts = fmaf(qp, km0, qn*km1);
    float to = fmaf(qn, km0, qp*km1);
    #pragma unroll
    for (int off = 1; off < 64; off <<= 1) { ts += __shfl_xor(ts, off); to += __shfl_xor(to, off); }
    const float z = 1.f / (((l < 32) ? ts : to) + 1e-6f);
    float acc = 0.f;
    #pragma unroll
    for (int d = 0; d < 64; d++) {
      const float pd = __shfl(qp, d);
      const float nd = __shfl(qn, d);
      acc = fmaf(pd, kvf_s[base1 + (d << 6)], acc);
      acc = fmaf(nd, kvf_s[base2 + (d << 6)], acc);
    }
    qxo[addr] = acc * z;   // same addr this thread read -> race-free in-place
  }
}

// -------- 5x5 depthwise conv + (xo+vd)*g, in place on head-major xo --------
__global__ __launch_bounds__(256) void conv_combine_kernel(
    const float* __restrict__ v, const float* __restrict__ dwc_w,
    const float* __restrict__ dwc_b, const float* __restrict__ g,
    float* __restrict__ xo)
{
  const int t = threadIdx.x;
  const int c = t & 63, xi = t >> 6;
  const int x = blockIdx.x*4 + xi, y = blockIdx.y;
  const int bh = blockIdx.z, b = bh >> 3, h = bh & 7;
  float w[25];
  #pragma unroll
  for (int i = 0; i < 25; i++) w[i] = dwc_w[c*25 + i];
  float acc = dwc_b[c];
  #pragma unroll
  for (int ky = 0; ky < 5; ky++) {
    const int yy = y + ky - 2;
    if (yy < 0 || yy >= 56) continue;
    #pragma unroll
    for (int kx = 0; kx < 5; kx++) {
      const int xx = x + kx - 2;
      if (xx < 0 || xx >= 56) continue;
      acc = fmaf(w[ky*5+kx], v[(((size_t)bh*NPOS + yy*56 + xx) << 6) + c], acc);
    }
  }
  const int n = y*56 + x;
  const size_t hm  = (((size_t)bh*NPOS + n) << 6) + c;
  const size_t nat = ((size_t)b*NPOS + n)*CC + h*64 + c;
  xo[hm] = (xo[hm] + acc) * g[nat];
}

// ---------------- launch ----------------
extern "C" void kernel_launch(void* const* d_in, const int* in_sizes, int n_in,
                              void* d_out, int out_size, void* d_ws, size_t ws_size,
                              hipStream_t stream)
{
  const float* x       = (const float*)d_in[0];
  const float* qg_w    = (const float*)d_in[1];
  const float* kv_w    = (const float*)d_in[2];
  const float* proj_w  = (const float*)d_in[3];
  const float* proj_b  = (const float*)d_in[4];
  const float* pos_enc = (const float*)d_in[5];
  const float* scale_p = (const float*)d_in[6];
  const float* power_p = (const float*)d_in[7];
  const float* dwc_w   = (const float*)d_in[8];
  const float* dwc_b   = (const float*)d_in[9];
  float* ws  = (float*)d_ws;
  float* out = (float*)d_out;

  const size_t MC = (size_t)MM * CC;                     // 25,690,112 floats
  float* bufA  = ws;                                     // k -> q -> xo -> combined (head-major)
  float* bufB  = ws + MC;                                // v head-major
  float* pkv   = ws + 2*MC;                              // SPLIT*128*8192
  float* pkm   = pkv + (size_t)SPLIT*128*8192;           // SPLIT*128*128
  float* kvf   = pkm + (size_t)SPLIT*128*128;            // 128*8192
  float* km    = kvf + (size_t)128*8192;                 // 128*128
  float* scinv = km + 128*128;                           // 512
  float* pwr   = scinv + 512;                            // 512
  float* g     = out;                                    // d_out doubles as g scratch

  const size_t need_bytes =
      (2*MC + (size_t)SPLIT*128*8192 + (size_t)SPLIT*128*128
       + (size_t)128*8192 + 128*128 + 1024) * sizeof(float);
  if (ws_size < need_bytes) return;  // diagnostic: clean zero-output failure, not a crash

  prep_kernel<<<1, 512, 0, stream>>>(scale_p, power_p, scinv, pwr);
  // kv GEMM first: k -> bufA, v -> bufB
  gemm_kernel<<<dim3(8, MM/BM), 256, 0, stream>>>(x, kv_w, 1024, 1, scinv, pos_enc, nullptr, bufA, bufB);
  reduce_kv_kernel<<<128*SPLIT, 256, 0, stream>>>(bufA, bufB, pwr, pkv, pkm);
  reduce_final_kernel<<<128, 256, 0, stream>>>(pkv, pkm, kvf, km);
  // qg GEMM: q -> bufA (k is dead), g -> d_out
  gemm_kernel<<<dim3(8, MM/BM), 256, 0, stream>>>(x, qg_w, 1024, 0, scinv, nullptr, nullptr, bufA, g);
  attn_kernel<<<dim3(NPOS/64, 128), 256, 0, stream>>>(bufA, kvf, km, pwr);
  conv_combine_kernel<<<dim3(14, 56, 128), 256, 0, stream>>>(bufB, dwc_w, dwc_b, g, bufA);
  // proj GEMM: head-major A (bufA) -> d_out (+bias)
  gemm_kernel<<<dim3(4, MM/BM), 256, 0, stream>>>(bufA, proj_w, 512, 2, nullptr, nullptr, proj_b, out, nullptr);
}

// Round 3
// 1349.092 us; speedup vs baseline: 2.5389x; 2.5389x over previous
//
#include <hip/hip_runtime.h>
#include <math.h>

typedef unsigned short ushort;
typedef __attribute__((ext_vector_type(8))) short short8v;
typedef __attribute__((ext_vector_type(4))) short short4v;
typedef __attribute__((ext_vector_type(4))) float float4v;
typedef __attribute__((ext_vector_type(8))) __bf16 bf16x8;

#define NHEADS 8
#define NPOS 3136
#define MROWS 50176          // 16*3136
#define KDIM 512

__device__ __forceinline__ ushort f2bf(float f) {
  union { float f; unsigned u; } x; x.f = f;
  unsigned r = x.u + 0x7fffu + ((x.u >> 16) & 1u);
  return (ushort)(r >> 16);
}
__device__ __forceinline__ float bf2f(ushort h) {
  union { unsigned u; float f; } x; x.u = ((unsigned)h) << 16; return x.f;
}

__device__ __forceinline__ float4v mfma16(short8v a, short8v b, float4v c) {
  return __builtin_amdgcn_mfma_f32_16x16x32_bf16(
      __builtin_bit_cast(bf16x8, a), __builtin_bit_cast(bf16x8, b), c, 0, 0, 0);
}

__device__ __forceinline__ void glds16(const void* g, void* l) {
  __builtin_amdgcn_global_load_lds(
      (const __attribute__((address_space(1))) unsigned int*)g,
      (__attribute__((address_space(3))) unsigned int*)l, 16, 0, 0);
}

// ---------------- prep: scale_inv, power ----------------
__global__ __launch_bounds__(512) void prep_kernel(const float* __restrict__ scale_p,
                                                   const float* __restrict__ power_p,
                                                   float* __restrict__ scinv,
                                                   float* __restrict__ pwr)
{
  int t = threadIdx.x;
  if (t < KDIM) {
    scinv[t] = 1.f / log1pf(expf(scale_p[t]));
    pwr[t]   = 1.f + 4.f / (1.f + expf(-power_p[t]));
  }
}

// ---------------- x fp32 -> bf16 ----------------
__global__ __launch_bounds__(256) void cvt_x_kernel(const float* __restrict__ x,
                                                    ushort* __restrict__ xb)
{
  const size_t i = ((size_t)blockIdx.x * 256 + threadIdx.x) * 4;
  float4v v = *(const float4v*)(x + i);
  short4v o = { (short)f2bf(v[0]), (short)f2bf(v[1]), (short)f2bf(v[2]), (short)f2bf(v[3]) };
  *(short4v*)(xb + i) = o;
}

// ---------------- weight transpose fp32[K][N] -> bf16[N][K] ----------------
__global__ __launch_bounds__(256) void transpose_w_kernel(const float* __restrict__ src,
                                                          ushort* __restrict__ dst,
                                                          int K, int N)
{
  __shared__ float tile[32][33];
  const int t = threadIdx.x, tx = t & 31, ty = t >> 5;
  const int nb = blockIdx.x * 32, kb = blockIdx.y * 32;
  #pragma unroll
  for (int i = 0; i < 4; i++)
    tile[ty + i*8][tx] = src[(size_t)(kb + ty + i*8) * N + nb + tx];
  __syncthreads();
  #pragma unroll
  for (int i = 0; i < 4; i++)
    dst[(size_t)(nb + ty + i*8) * K + kb + tx] = f2bf(tile[tx][ty + i*8]);
}

// ---------------- bf16 MFMA GEMM 128x128xK512 ----------------
// A bf16 [M][512]; Bt bf16 [N][512]. C[m][n] = sum_k A[m][k]*Bt[n][k]
// mode 0 (qg): col<512 -> q features into QS (outb0); col>=512 -> g fp32 (outf=d_out)
// mode 1 (kv): col<512 -> k features (pos_enc+scale) into KF (outb0); col>=512 -> v bf16 head-major (outb1)
// mode 2 (proj): outf = d_out natural fp32 + bias
__global__ __launch_bounds__(256) void gemm_bf16_kernel(
    const ushort* __restrict__ A, const ushort* __restrict__ Bt, int mode,
    const float* __restrict__ scinv, const float* __restrict__ pwr,
    const float* __restrict__ pos_enc, const float* __restrict__ bias,
    float* __restrict__ outf, ushort* __restrict__ outb0, ushort* __restrict__ outb1)
{
  __shared__ ushort As[128*32];
  __shared__ ushort Bs[128*32];
  const int t = threadIdx.x;
  const int wave = t >> 6, lane = t & 63;
  const int m0 = blockIdx.y * 128, n0 = blockIdx.x * 128;
  const int wm = wave >> 1, wn = wave & 1;
  const int rA = lane >> 2;            // row within 16-row staging group
  const int kc = (lane & 3) * 8;       // k-offset (shorts)

  float4v acc[4][4];
  #pragma unroll
  for (int i = 0; i < 4; i++)
    #pragma unroll
    for (int j = 0; j < 4; j++) { float4v z = {0.f,0.f,0.f,0.f}; acc[i][j] = z; }

  for (int k0 = 0; k0 < KDIM; k0 += 32) {
    __syncthreads();
    #pragma unroll
    for (int j = 0; j < 2; j++) {
      const int ra = wave*32 + j*16;
      glds16(A  + (size_t)(m0 + ra + rA)*KDIM + k0 + kc, &As[ra*32]);
      glds16(Bt + (size_t)(n0 + ra + rA)*KDIM + k0 + kc, &Bs[ra*32]);
    }
    __syncthreads();
    const int lm = lane & 15, q8 = (lane >> 4) * 8;
    short8v a[4], b[4];
    #pragma unroll
    for (int i = 0; i < 4; i++) {
      a[i] = *(const short8v*)&As[(wm*64 + i*16 + lm)*32 + q8];
      b[i] = *(const short8v*)&Bs[(wn*64 + i*16 + lm)*32 + q8];
    }
    #pragma unroll
    for (int i = 0; i < 4; i++)
      #pragma unroll
      for (int j = 0; j < 4; j++)
        acc[i][j] = mfma16(a[i], b[j], acc[i][j]);
  }

  const int lm = lane & 15, rq = (lane >> 4) * 4;
  #pragma unroll
  for (int i = 0; i < 4; i++) {
    #pragma unroll
    for (int r = 0; r < 4; r++) {
      const int grow = m0 + wm*64 + i*16 + rq + r;
      const int bb = grow / NPOS;
      const int nn = grow - bb * NPOS;
      #pragma unroll
      for (int j = 0; j < 4; j++) {
        const int gcol = n0 + wn*64 + j*16 + lm;
        const float val = acc[i][j][r];
        if (mode == 2) {
          outf[(size_t)grow * 512 + gcol] = val + bias[gcol];
        } else if (gcol < 512) {
          float sv;
          if (mode == 0) sv = val * scinv[gcol];
          else           sv = (val + pos_enc[(size_t)nn*512 + gcol]) * scinv[gcol];
          const float p = pwr[gcol];
          const float aq = fabsf(sv);
          float f = 0.f;
          if (aq > 0.f) f = exp2f(p * log2f(aq));
          const int h = gcol >> 6, d = gcol & 63;
          ushort* qrow = outb0 + (((size_t)((bb << 3) + h) * NPOS + nn) << 7);
          const ushort fb = f2bf(f);
          if (sv > 0.f)      { qrow[d] = fb; qrow[64 + d] = 0; }
          else if (sv < 0.f) { qrow[d] = 0;  qrow[64 + d] = fb; }
          else               { qrow[d] = 0;  qrow[64 + d] = 0; }
        } else {
          const int c2 = gcol - 512;
          const int h = c2 >> 6, d = c2 & 63;
          if (mode == 0) outf[(size_t)grow * 512 + c2] = val;  // g fp32 natural
          else outb1[(((size_t)((bb << 3) + h) * NPOS + nn) << 6) + d] = f2bf(val);
        }
      }
    }
  }
}

// ---------------- kf outer-product partial reduction ----------------
#define RSPLIT 8
#define RCHUNK 392
__global__ __launch_bounds__(256) void reduce_kv_kernel(
    const ushort* __restrict__ KF, const ushort* __restrict__ Vb,
    float* __restrict__ pkv, float* __restrict__ pkm)
{
  const int bh = blockIdx.x >> 3, s = blockIdx.x & 7;
  const int t = threadIdx.x;
  __shared__ ushort kf_s[8*128];
  __shared__ ushort v_s[8*64];
  const int td = t & 31, te = t >> 5;
  const int d4 = td * 4, e8 = te * 8;
  float acc[4][8];
  #pragma unroll
  for (int c = 0; c < 4; c++)
    #pragma unroll
    for (int e = 0; e < 8; e++) acc[c][e] = 0.f;
  float km4[4] = {0.f,0.f,0.f,0.f};
  const int nbase = s * RCHUNK;

  for (int g = 0; g < RCHUNK/8; g++) {
    const int n = nbase + g*8;
    *(short4v*)&kf_s[(t>>5)*128 + (t&31)*4] =
        *(const short4v*)&KF[(((size_t)bh*NPOS + n + (t>>5)) << 7) + (t&31)*4];
    if (t < 128)
      *(short4v*)&v_s[(t>>4)*64 + (t&15)*4] =
          *(const short4v*)&Vb[(((size_t)bh*NPOS + n + (t>>4)) << 6) + (t&15)*4];
    __syncthreads();
    #pragma unroll
    for (int i = 0; i < 8; i++) {
      short4v k4 = *(const short4v*)&kf_s[i*128 + d4];
      short8v v8 = *(const short8v*)&v_s[i*64 + e8];
      float kf4[4], vf[8];
      #pragma unroll
      for (int c = 0; c < 4; c++) kf4[c] = bf2f((ushort)k4[c]);
      #pragma unroll
      for (int e = 0; e < 8; e++) vf[e] = bf2f((ushort)v8[e]);
      if (te == 0) {
        #pragma unroll
        for (int c = 0; c < 4; c++) km4[c] += kf4[c];
      }
      #pragma unroll
      for (int c = 0; c < 4; c++)
        #pragma unroll
        for (int e = 0; e < 8; e++) acc[c][e] = fmaf(kf4[c], vf[e], acc[c][e]);
    }
    __syncthreads();
  }
  float* op = pkv + ((size_t)(s*128 + bh) << 13);
  #pragma unroll
  for (int c = 0; c < 4; c++) {
    float4v o0 = {acc[c][0], acc[c][1], acc[c][2], acc[c][3]};
    float4v o1 = {acc[c][4], acc[c][5], acc[c][6], acc[c][7]};
    *(float4v*)&op[(d4+c)*64 + e8]     = o0;
    *(float4v*)&op[(d4+c)*64 + e8 + 4] = o1;
  }
  if (te == 0) {
    #pragma unroll
    for (int c = 0; c < 4; c++) pkm[((size_t)(s*128 + bh) << 7) + d4 + c] = km4[c];
  }
}

// ---------------- final reduce -> kvf2^T bf16 [bh][80][128] ----------------
__global__ __launch_bounds__(256) void reduce_final_kernel(
    const float* __restrict__ pkv, const float* __restrict__ pkm,
    ushort* __restrict__ Kt)
{
  const int bh = blockIdx.x, t = threadIdx.x;
  const float inv_n = 1.f / (float)NPOS;
  for (int i = t; i < 8192; i += 256) {
    float s = 0.f;
    #pragma unroll
    for (int sp = 0; sp < RSPLIT; sp++) s += pkv[((size_t)(sp*128 + bh) << 13) + i];
    const int d = i >> 6, e = i & 63;
    const int dd = (e < 32) ? d : (d ^ 64);
    Kt[((size_t)bh*80 + e)*128 + dd] = f2bf(s * inv_n);
  }
  if (t < 128) {
    float s = 0.f;
    #pragma unroll
    for (int sp = 0; sp < RSPLIT; sp++) s += pkm[((size_t)(sp*128 + bh) << 7) + t];
    const ushort b = f2bf(s * inv_n);
    Kt[((size_t)bh*80 + 64)*128 + t] = b;          // km (denom_sim column)
    Kt[((size_t)bh*80 + 65)*128 + (t ^ 64)] = b;   // km swapped (denom_opp)
  }
  for (int i = t; i < 14*128; i += 256) Kt[((size_t)bh*80 + 66)*128 + i] = 0;
}

// ---------------- attention apply: MFMA [128x80] = QS[128x128] @ Kt^T -------
__global__ __launch_bounds__(256) void attn_mfma_kernel(
    const ushort* __restrict__ QS, const ushort* __restrict__ Kt,
    ushort* __restrict__ XO)
{
  __shared__ ushort qs_s[128*128];
  __shared__ ushort kv_s[80*128];
  const int t = threadIdx.x, wave = t >> 6, lane = t & 63;
  const int bh = blockIdx.y;
  const int n0 = blockIdx.x * 128;

  const ushort* ksrc = Kt + (size_t)bh * 80 * 128;
  #pragma unroll
  for (int j = 0; j < 5; j++) {
    const int elem = (j*4096 + wave*1024) >> 1;
    glds16(ksrc + elem + lane*8, kv_s + elem);
  }
  const ushort* qsrc = QS + ((size_t)bh * NPOS + n0) * 128;
  #pragma unroll
  for (int j = 0; j < 8; j++) {
    const int elem = (j*4096 + wave*1024) >> 1;
    glds16(qsrc + elem + lane*8, qs_s + elem);
  }
  __syncthreads();

  const int lm = lane & 15, q8 = (lane >> 4) * 8;
  float4v acc[2][5];
  #pragma unroll
  for (int i = 0; i < 2; i++)
    #pragma unroll
    for (int j = 0; j < 5; j++) { float4v z = {0.f,0.f,0.f,0.f}; acc[i][j] = z; }

  #pragma unroll
  for (int ks = 0; ks < 4; ks++) {
    short8v a[2], b[5];
    #pragma unroll
    for (int i = 0; i < 2; i++)
      a[i] = *(const short8v*)&qs_s[(wave*32 + i*16 + lm)*128 + ks*32 + q8];
    #pragma unroll
    for (int j = 0; j < 5; j++)
      b[j] = *(const short8v*)&kv_s[(j*16 + lm)*128 + ks*32 + q8];
    #pragma unroll
    for (int i = 0; i < 2; i++)
      #pragma unroll
      for (int j = 0; j < 5; j++)
        acc[i][j] = mfma16(a[i], b[j], acc[i][j]);
  }

  const int rq = (lane >> 4) * 4;
  #pragma unroll
  for (int i = 0; i < 2; i++) {
    #pragma unroll
    for (int r = 0; r < 4; r++) {
      const int n = n0 + wave*32 + i*16 + rq + r;
      const float dsim = __shfl(acc[i][4][r], lane & 48);
      const float dopp = __shfl(acc[i][4][r], (lane & 48) | 1);
      const float zs = 1.f / (dsim + 1e-6f);
      const float zo = 1.f / (dopp + 1e-6f);
      if (n < NPOS) {
        ushort* orow = XO + (((size_t)bh * NPOS + n) << 6);
        #pragma unroll
        for (int j = 0; j < 4; j++)
          orow[j*16 + lm] = f2bf(acc[i][j][r] * ((j < 2) ? zs : zo));
      }
    }
  }
}

// ------- 5x5 depthwise conv + (xo+vd)*g -> combined bf16 natural -------
__global__ __launch_bounds__(256) void conv_combine_kernel(
    const ushort* __restrict__ Vb, const ushort* __restrict__ XO,
    const float* __restrict__ g, const float* __restrict__ dwc_w,
    const float* __restrict__ dwc_b, ushort* __restrict__ cmb)
{
  __shared__ ushort vs[9*56*64];   // 64512 B
  const int t = threadIdx.x;
  const int bh = blockIdx.y, b = bh >> 3, h = bh & 7;
  const int y0 = blockIdx.x * 5;
  for (int i = t; i < 9*896; i += 256) {       // 896 short4 per image row
    const int ry = i / 896, off = (i - ry*896) * 4;
    const int yy = y0 - 2 + ry;
    short4v val = {0,0,0,0};
    if (yy >= 0 && yy < 56)
      val = *(const short4v*)&Vb[(((size_t)bh*NPOS + yy*56) << 6) + off];
    *(short4v*)&vs[ry*3584 + off] = val;
  }
  __syncthreads();
  const int c = t & 63, xg = t >> 6;
  float w[25];
  #pragma unroll
  for (int i = 0; i < 25; i++) w[i] = dwc_w[c*25 + i];
  const float bias = dwc_b[c];
  for (int yl = 0; yl < 5; yl++) {
    const int y = y0 + yl;
    if (y >= 56) break;
    for (int xi = 0; xi < 14; xi++) {
      const int x = xg*14 + xi;
      float a = bias;
      #pragma unroll
      for (int ky = 0; ky < 5; ky++) {
        #pragma unroll
        for (int kx = 0; kx < 5; kx++) {
          const int xx = x + kx - 2;
          if (xx >= 0 && xx < 56)
            a = fmaf(w[ky*5+kx], bf2f(vs[(yl+ky)*3584 + (xx << 6) + c]), a);
        }
      }
      const int n = y*56 + x;
      const float xov = bf2f(XO[(((size_t)bh*NPOS + n) << 6) + c]);
      const size_t nat = ((size_t)b*NPOS + n)*512 + h*64 + c;
      cmb[nat] = f2bf((xov + a) * g[nat]);
    }
  }
}

// ---------------- launch ----------------
extern "C" void kernel_launch(void* const* d_in, const int* in_sizes, int n_in,
                              void* d_out, int out_size, void* d_ws, size_t ws_size,
                              hipStream_t stream)
{
  const float* x       = (const float*)d_in[0];
  const float* qg_w    = (const float*)d_in[1];
  const float* kv_w    = (const float*)d_in[2];
  const float* proj_w  = (const float*)d_in[3];
  const float* proj_b  = (const float*)d_in[4];
  const float* pos_enc = (const float*)d_in[5];
  const float* scale_p = (const float*)d_in[6];
  const float* power_p = (const float*)d_in[7];
  const float* dwc_w   = (const float*)d_in[8];
  const float* dwc_b   = (const float*)d_in[9];
  float* out = (float*)d_out;

  const size_t MCs = (size_t)MROWS * 512;        // 25,690,112
  ushort* xbf = (ushort*)d_ws;                   // x bf16 -> later XO bf16 head-major
  ushort* KQ  = xbf + MCs;                       // KF -> QS [128][3136][128] (+pad) -> later cmb
  ushort* Vb  = KQ + 2*MCs + 8192;               // v bf16 head-major
  ushort* Kt  = Vb + MCs;                        // kvf2^T bf16 [128][80][128]
  ushort* wqg = Kt + (size_t)128*80*128;         // qg_w^T bf16 [1024][512]
  ushort* wkv = wqg + (size_t)1024*512;
  ushort* wpj = wkv + (size_t)1024*512;          // proj_w^T bf16 [512][512]
  float* pkv  = (float*)(wpj + (size_t)512*512); // 8*128*8192
  float* pkm  = pkv + (size_t)RSPLIT*128*8192;   // 8*128*128
  float* scinv= pkm + (size_t)RSPLIT*128*128;
  float* pwr  = scinv + 512;
  const size_t need = (size_t)((char*)(pwr + 512) - (char*)d_ws);
  if (ws_size < need) return;

  ushort* XOb = xbf;   // aliases x_bf (dead after qg GEMM)
  ushort* cmb = KQ;    // aliases QS (dead after attn)
  float* gbuf = out;   // d_out doubles as g scratch

  prep_kernel<<<1, 512, 0, stream>>>(scale_p, power_p, scinv, pwr);
  cvt_x_kernel<<<(int)(MCs/4/256), 256, 0, stream>>>(x, xbf);
  transpose_w_kernel<<<dim3(32,16), 256, 0, stream>>>(qg_w,   wqg, 512, 1024);
  transpose_w_kernel<<<dim3(32,16), 256, 0, stream>>>(kv_w,   wkv, 512, 1024);
  transpose_w_kernel<<<dim3(16,16), 256, 0, stream>>>(proj_w, wpj, 512, 512);

  // kv GEMM: KF features + v bf16
  gemm_bf16_kernel<<<dim3(8, MROWS/128), 256, 0, stream>>>(
      xbf, wkv, 1, scinv, pwr, pos_enc, nullptr, nullptr, KQ, Vb);
  reduce_kv_kernel<<<128*RSPLIT, 256, 0, stream>>>(KQ, Vb, pkv, pkm);
  reduce_final_kernel<<<128, 256, 0, stream>>>(pkv, pkm, Kt);
  // qg GEMM: QS features + g fp32 (into d_out)
  gemm_bf16_kernel<<<dim3(8, MROWS/128), 256, 0, stream>>>(
      xbf, wqg, 0, scinv, pwr, nullptr, nullptr, gbuf, KQ, nullptr);
  attn_mfma_kernel<<<dim3(25, 128), 256, 0, stream>>>(KQ, Kt, XOb);
  conv_combine_kernel<<<dim3(12, 128), 256, 0, stream>>>(Vb, XOb, gbuf, dwc_w, dwc_b, cmb);
  // proj GEMM
  gemm_bf16_kernel<<<dim3(4, MROWS/128), 256, 0, stream>>>(
      cmb, wpj, 2, nullptr, nullptr, nullptr, proj_b, out, nullptr, nullptr);
}

// Round 4
// 1082.272 us; speedup vs baseline: 3.1648x; 1.2465x over previous
//
#include <hip/hip_runtime.h>
#include <math.h>

typedef unsigned short ushort;
typedef __attribute__((ext_vector_type(8))) short short8v;
typedef __attribute__((ext_vector_type(4))) short short4v;
typedef __attribute__((ext_vector_type(4))) float float4v;
typedef __attribute__((ext_vector_type(8))) __bf16 bf16x8;

#define NHEADS 8
#define NPOS 3136
#define MROWS 50176          // 16*3136
#define KDIM 512

__device__ __forceinline__ ushort f2bf(float f) {
  union { float f; unsigned u; } x; x.f = f;
  unsigned r = x.u + 0x7fffu + ((x.u >> 16) & 1u);
  return (ushort)(r >> 16);
}
__device__ __forceinline__ float bf2f(ushort h) {
  union { unsigned u; float f; } x; x.u = ((unsigned)h) << 16; return x.f;
}

__device__ __forceinline__ float4v mfma16(short8v a, short8v b, float4v c) {
  return __builtin_amdgcn_mfma_f32_16x16x32_bf16(
      __builtin_bit_cast(bf16x8, a), __builtin_bit_cast(bf16x8, b), c, 0, 0, 0);
}

__device__ __forceinline__ void glds16(const void* g, void* l) {
  __builtin_amdgcn_global_load_lds(
      (const __attribute__((address_space(1))) unsigned int*)g,
      (__attribute__((address_space(3))) unsigned int*)l, 16, 0, 0);
}

// ---------------- prep: scale_inv, power ----------------
__global__ __launch_bounds__(512) void prep_kernel(const float* __restrict__ scale_p,
                                                   const float* __restrict__ power_p,
                                                   float* __restrict__ scinv,
                                                   float* __restrict__ pwr)
{
  int t = threadIdx.x;
  if (t < KDIM) {
    scinv[t] = 1.f / log1pf(expf(scale_p[t]));
    pwr[t]   = 1.f + 4.f / (1.f + expf(-power_p[t]));
  }
}

// ---------------- x fp32 -> bf16 ----------------
__global__ __launch_bounds__(256) void cvt_x_kernel(const float* __restrict__ x,
                                                    ushort* __restrict__ xb)
{
  const size_t i = ((size_t)blockIdx.x * 256 + threadIdx.x) * 4;
  float4v v = *(const float4v*)(x + i);
  short4v o = { (short)f2bf(v[0]), (short)f2bf(v[1]), (short)f2bf(v[2]), (short)f2bf(v[3]) };
  *(short4v*)(xb + i) = o;
}

// ---------------- weight transpose fp32[K][N] -> bf16[N][K] ----------------
__global__ __launch_bounds__(256) void transpose_w_kernel(const float* __restrict__ src,
                                                          ushort* __restrict__ dst,
                                                          int K, int N)
{
  __shared__ float tile[32][33];
  const int t = threadIdx.x, tx = t & 31, ty = t >> 5;
  const int nb = blockIdx.x * 32, kb = blockIdx.y * 32;
  #pragma unroll
  for (int i = 0; i < 4; i++)
    tile[ty + i*8][tx] = src[(size_t)(kb + ty + i*8) * N + nb + tx];
  __syncthreads();
  #pragma unroll
  for (int i = 0; i < 4; i++)
    dst[(size_t)(nb + ty + i*8) * K + kb + tx] = f2bf(tile[tx][ty + i*8]);
}

// ---------------- bf16 MFMA GEMM 128x128xK512 ----------------
// A bf16 [M][512]; Bt bf16 [N][512]. C[m][n] = sum_k A[m][k]*Bt[n][k]
// mode 0 (qg): col<512 -> q features into QS (outb0); col>=512 -> g bf16 natural (outb1)
// mode 1 (kv): col<512 -> k features (pos_enc+scale) into KF (outb0); col>=512 -> v bf16 head-major (outb1)
// mode 2 (proj): outf = d_out natural fp32 + bias
__global__ __launch_bounds__(256) void gemm_bf16_kernel(
    const ushort* __restrict__ A, const ushort* __restrict__ Bt, int mode,
    const float* __restrict__ scinv, const float* __restrict__ pwr,
    const float* __restrict__ pos_enc, const float* __restrict__ bias,
    float* __restrict__ outf, ushort* __restrict__ outb0, ushort* __restrict__ outb1)
{
  __shared__ ushort As[128*32];
  __shared__ ushort Bs[128*32];
  const int t = threadIdx.x;
  const int wave = t >> 6, lane = t & 63;
  const int m0 = blockIdx.y * 128, n0 = blockIdx.x * 128;
  const int wm = wave >> 1, wn = wave & 1;
  const int rA = lane >> 2;            // row within 16-row staging group
  const int kc = (lane & 3) * 8;       // k-offset (shorts)

  float4v acc[4][4];
  #pragma unroll
  for (int i = 0; i < 4; i++)
    #pragma unroll
    for (int j = 0; j < 4; j++) { float4v z = {0.f,0.f,0.f,0.f}; acc[i][j] = z; }

  for (int k0 = 0; k0 < KDIM; k0 += 32) {
    __syncthreads();
    #pragma unroll
    for (int j = 0; j < 2; j++) {
      const int ra = wave*32 + j*16;
      glds16(A  + (size_t)(m0 + ra + rA)*KDIM + k0 + kc, &As[ra*32]);
      glds16(Bt + (size_t)(n0 + ra + rA)*KDIM + k0 + kc, &Bs[ra*32]);
    }
    __syncthreads();
    const int lm = lane & 15, q8 = (lane >> 4) * 8;
    short8v a[4], b[4];
    #pragma unroll
    for (int i = 0; i < 4; i++) {
      a[i] = *(const short8v*)&As[(wm*64 + i*16 + lm)*32 + q8];
      b[i] = *(const short8v*)&Bs[(wn*64 + i*16 + lm)*32 + q8];
    }
    #pragma unroll
    for (int i = 0; i < 4; i++)
      #pragma unroll
      for (int j = 0; j < 4; j++)
        acc[i][j] = mfma16(a[i], b[j], acc[i][j]);
  }

  const int lm = lane & 15, rq = (lane >> 4) * 4;
  #pragma unroll
  for (int i = 0; i < 4; i++) {
    #pragma unroll
    for (int r = 0; r < 4; r++) {
      const int grow = m0 + wm*64 + i*16 + rq + r;
      const int bb = grow / NPOS;
      const int nn = grow - bb * NPOS;
      #pragma unroll
      for (int j = 0; j < 4; j++) {
        const int gcol = n0 + wn*64 + j*16 + lm;
        const float val = acc[i][j][r];
        if (mode == 2) {
          outf[(size_t)grow * 512 + gcol] = val + bias[gcol];
        } else if (gcol < 512) {
          float sv;
          if (mode == 0) sv = val * scinv[gcol];
          else           sv = (val + pos_enc[(size_t)nn*512 + gcol]) * scinv[gcol];
          const float p = pwr[gcol];
          const float aq = fabsf(sv);
          float f = 0.f;
          if (aq > 0.f) f = exp2f(p * log2f(aq));
          const int h = gcol >> 6, d = gcol & 63;
          ushort* qrow = outb0 + (((size_t)((bb << 3) + h) * NPOS + nn) << 7);
          const ushort fb = f2bf(f);
          if (sv > 0.f)      { qrow[d] = fb; qrow[64 + d] = 0; }
          else if (sv < 0.f) { qrow[d] = 0;  qrow[64 + d] = fb; }
          else               { qrow[d] = 0;  qrow[64 + d] = 0; }
        } else {
          const int c2 = gcol - 512;
          if (mode == 0) {
            outb1[(size_t)grow * 512 + c2] = f2bf(val);        // g bf16 natural (d_out low half)
          } else {
            const int h = c2 >> 6, d = c2 & 63;
            outb1[(((size_t)((bb << 3) + h) * NPOS + nn) << 6) + d] = f2bf(val);
          }
        }
      }
    }
  }
}

// ---------------- kf outer-product partial reduction ----------------
#define RSPLIT 8
#define RCHUNK 392
__global__ __launch_bounds__(256) void reduce_kv_kernel(
    const ushort* __restrict__ KF, const ushort* __restrict__ Vb,
    float* __restrict__ pkv, float* __restrict__ pkm)
{
  const int bh = blockIdx.x >> 3, s = blockIdx.x & 7;
  const int t = threadIdx.x;
  __shared__ ushort kf_s[8*128];
  __shared__ ushort v_s[8*64];
  const int td = t & 31, te = t >> 5;
  const int d4 = td * 4, e8 = te * 8;
  float acc[4][8];
  #pragma unroll
  for (int c = 0; c < 4; c++)
    #pragma unroll
    for (int e = 0; e < 8; e++) acc[c][e] = 0.f;
  float km4[4] = {0.f,0.f,0.f,0.f};
  const int nbase = s * RCHUNK;

  for (int g = 0; g < RCHUNK/8; g++) {
    const int n = nbase + g*8;
    *(short4v*)&kf_s[(t>>5)*128 + (t&31)*4] =
        *(const short4v*)&KF[(((size_t)bh*NPOS + n + (t>>5)) << 7) + (t&31)*4];
    if (t < 128)
      *(short4v*)&v_s[(t>>4)*64 + (t&15)*4] =
          *(const short4v*)&Vb[(((size_t)bh*NPOS + n + (t>>4)) << 6) + (t&15)*4];
    __syncthreads();
    #pragma unroll
    for (int i = 0; i < 8; i++) {
      short4v k4 = *(const short4v*)&kf_s[i*128 + d4];
      short8v v8 = *(const short8v*)&v_s[i*64 + e8];
      float kf4[4], vf[8];
      #pragma unroll
      for (int c = 0; c < 4; c++) kf4[c] = bf2f((ushort)k4[c]);
      #pragma unroll
      for (int e = 0; e < 8; e++) vf[e] = bf2f((ushort)v8[e]);
      if (te == 0) {
        #pragma unroll
        for (int c = 0; c < 4; c++) km4[c] += kf4[c];
      }
      #pragma unroll
      for (int c = 0; c < 4; c++)
        #pragma unroll
        for (int e = 0; e < 8; e++) acc[c][e] = fmaf(kf4[c], vf[e], acc[c][e]);
    }
    __syncthreads();
  }
  float* op = pkv + ((size_t)(s*128 + bh) << 13);
  #pragma unroll
  for (int c = 0; c < 4; c++) {
    float4v o0 = {acc[c][0], acc[c][1], acc[c][2], acc[c][3]};
    float4v o1 = {acc[c][4], acc[c][5], acc[c][6], acc[c][7]};
    *(float4v*)&op[(d4+c)*64 + e8]     = o0;
    *(float4v*)&op[(d4+c)*64 + e8 + 4] = o1;
  }
  if (te == 0) {
    #pragma unroll
    for (int c = 0; c < 4; c++) pkm[((size_t)(s*128 + bh) << 7) + d4 + c] = km4[c];
  }
}

// ---------------- final reduce -> kvf2^T bf16 [bh][80][128] ----------------
__global__ __launch_bounds__(256) void reduce_final_kernel(
    const float* __restrict__ pkv, const float* __restrict__ pkm,
    ushort* __restrict__ Kt)
{
  const int bh = blockIdx.x, t = threadIdx.x;
  const float inv_n = 1.f / (float)NPOS;
  for (int i = t; i < 8192; i += 256) {
    float s = 0.f;
    #pragma unroll
    for (int sp = 0; sp < RSPLIT; sp++) s += pkv[((size_t)(sp*128 + bh) << 13) + i];
    const int d = i >> 6, e = i & 63;
    const int dd = (e < 32) ? d : (d ^ 64);
    Kt[((size_t)bh*80 + e)*128 + dd] = f2bf(s * inv_n);
  }
  if (t < 128) {
    float s = 0.f;
    #pragma unroll
    for (int sp = 0; sp < RSPLIT; sp++) s += pkm[((size_t)(sp*128 + bh) << 7) + t];
    const ushort b = f2bf(s * inv_n);
    Kt[((size_t)bh*80 + 64)*128 + t] = b;          // km (denom_sim column)
    Kt[((size_t)bh*80 + 65)*128 + (t ^ 64)] = b;   // km swapped (denom_opp)
  }
  for (int i = t; i < 14*128; i += 256) Kt[((size_t)bh*80 + 66)*128 + i] = 0;
}

// ---------------- attention apply: MFMA [128x80] = QS[128x128] @ Kt^T -------
__global__ __launch_bounds__(256) void attn_mfma_kernel(
    const ushort* __restrict__ QS, const ushort* __restrict__ Kt,
    ushort* __restrict__ XO)
{
  __shared__ ushort qs_s[128*128];
  __shared__ ushort kv_s[80*128];
  const int t = threadIdx.x, wave = t >> 6, lane = t & 63;
  const int bh = blockIdx.y;
  const int n0 = blockIdx.x * 128;

  const ushort* ksrc = Kt + (size_t)bh * 80 * 128;
  #pragma unroll
  for (int j = 0; j < 5; j++) {
    const int elem = (j*4096 + wave*1024) >> 1;
    glds16(ksrc + elem + lane*8, kv_s + elem);
  }
  const ushort* qsrc = QS + ((size_t)bh * NPOS + n0) * 128;
  #pragma unroll
  for (int j = 0; j < 8; j++) {
    const int elem = (j*4096 + wave*1024) >> 1;
    glds16(qsrc + elem + lane*8, qs_s + elem);
  }
  __syncthreads();

  const int lm = lane & 15, q8 = (lane >> 4) * 8;
  float4v acc[2][5];
  #pragma unroll
  for (int i = 0; i < 2; i++)
    #pragma unroll
    for (int j = 0; j < 5; j++) { float4v z = {0.f,0.f,0.f,0.f}; acc[i][j] = z; }

  #pragma unroll
  for (int ks = 0; ks < 4; ks++) {
    short8v a[2], b[5];
    #pragma unroll
    for (int i = 0; i < 2; i++)
      a[i] = *(const short8v*)&qs_s[(wave*32 + i*16 + lm)*128 + ks*32 + q8];
    #pragma unroll
    for (int j = 0; j < 5; j++)
      b[j] = *(const short8v*)&kv_s[(j*16 + lm)*128 + ks*32 + q8];
    #pragma unroll
    for (int i = 0; i < 2; i++)
      #pragma unroll
      for (int j = 0; j < 5; j++)
        acc[i][j] = mfma16(a[i], b[j], acc[i][j]);
  }

  const int rq = (lane >> 4) * 4;
  #pragma unroll
  for (int i = 0; i < 2; i++) {
    #pragma unroll
    for (int r = 0; r < 4; r++) {
      const int n = n0 + wave*32 + i*16 + rq + r;
      const float dsim = __shfl(acc[i][4][r], lane & 48);
      const float dopp = __shfl(acc[i][4][r], (lane & 48) | 1);
      const float zs = 1.f / (dsim + 1e-6f);
      const float zo = 1.f / (dopp + 1e-6f);
      if (n < NPOS) {
        ushort* orow = XO + (((size_t)bh * NPOS + n) << 6);
        #pragma unroll
        for (int j = 0; j < 4; j++)
          orow[j*16 + lm] = f2bf(acc[i][j][r] * ((j < 2) ? zs : zo));
      }
    }
  }
}

// ------- 5x5 depthwise conv + (xo+vd)*g -> combined bf16 natural -------
// Block: (ystrip of 2, bh). LDS: 6 rows x 60 padded-x x 64 c (zero-padded in x/y).
// Scatter pattern: each loaded tap value feeds 5 independent accumulators.
__global__ __launch_bounds__(256) void conv_combine_kernel(
    const ushort* __restrict__ Vb, const ushort* __restrict__ XO,
    const ushort* __restrict__ g, const float* __restrict__ dwc_w,
    const float* __restrict__ dwc_b, ushort* __restrict__ cmb)
{
  __shared__ ushort vs[6*60*64];   // 46080 B -> 3 blocks/CU
  const int t = threadIdx.x;
  const int bh = blockIdx.y, b = bh >> 3, h = bh & 7;
  const int y0 = blockIdx.x * 2;
  // stage rows y0-2..y0+3, x in [-2,58), zero-padded
  for (int i = t; i < 5760; i += 256) {
    const int ry = i / 960;
    const int rem = i - ry * 960;
    const int xx = (rem >> 4) - 2;
    const int c4 = (rem & 15) * 4;
    const int yy = y0 - 2 + ry;
    short4v val = {0,0,0,0};
    if (yy >= 0 && yy < 56 && xx >= 0 && xx < 56)
      val = *(const short4v*)&Vb[(((size_t)bh*NPOS + yy*56 + xx) << 6) + c4];
    *(short4v*)&vs[ry*3840 + (rem >> 4)*64 + c4] = val;
  }
  __syncthreads();

  const int c = t & 63, xg = t >> 6;   // 4 x-groups of 14
  float w[25];
  #pragma unroll
  for (int i = 0; i < 25; i++) w[i] = dwc_w[c*25 + i];
  const float bias = dwc_b[c];

  #pragma unroll
  for (int y = 0; y < 2; y++) {
    float acc[14];
    #pragma unroll
    for (int xi = 0; xi < 14; xi++) acc[xi] = bias;
    #pragma unroll
    for (int ky = 0; ky < 5; ky++) {
      const ushort* row = &vs[(y + ky)*3840 + (xg*14)*64 + c];
      #pragma unroll
      for (int xl = 0; xl < 18; xl++) {
        const float val = bf2f(row[xl*64]);
        #pragma unroll
        for (int kx = 0; kx < 5; kx++) {
          const int xi = xl - kx;
          if (xi >= 0 && xi < 14)
            acc[xi] = fmaf(w[ky*5 + kx], val, acc[xi]);
        }
      }
    }
    const int yo = y0 + y;
    #pragma unroll
    for (int xi = 0; xi < 14; xi++) {
      const int n = yo*56 + xg*14 + xi;
      const float xov = bf2f(XO[(((size_t)bh*NPOS + n) << 6) + c]);
      const size_t nat = ((size_t)b*NPOS + n)*512 + h*64 + c;
      cmb[nat] = f2bf((xov + acc[xi]) * bf2f(g[nat]));
    }
  }
}

// ---------------- launch ----------------
extern "C" void kernel_launch(void* const* d_in, const int* in_sizes, int n_in,
                              void* d_out, int out_size, void* d_ws, size_t ws_size,
                              hipStream_t stream)
{
  const float* x       = (const float*)d_in[0];
  const float* qg_w    = (const float*)d_in[1];
  const float* kv_w    = (const float*)d_in[2];
  const float* proj_w  = (const float*)d_in[3];
  const float* proj_b  = (const float*)d_in[4];
  const float* pos_enc = (const float*)d_in[5];
  const float* scale_p = (const float*)d_in[6];
  const float* power_p = (const float*)d_in[7];
  const float* dwc_w   = (const float*)d_in[8];
  const float* dwc_b   = (const float*)d_in[9];
  float* out = (float*)d_out;

  const size_t MCs = (size_t)MROWS * 512;        // 25,690,112
  ushort* xbf = (ushort*)d_ws;                   // x bf16 -> later XO bf16 head-major
  ushort* KQ  = xbf + MCs;                       // KF -> QS [128][3136][128] (+pad) -> later cmb
  ushort* Vb  = KQ + 2*MCs + 8192;               // v bf16 head-major
  ushort* Kt  = Vb + MCs;                        // kvf2^T bf16 [128][80][128]
  ushort* wqg = Kt + (size_t)128*80*128;         // qg_w^T bf16 [1024][512]
  ushort* wkv = wqg + (size_t)1024*512;
  ushort* wpj = wkv + (size_t)1024*512;          // proj_w^T bf16 [512][512]
  float* pkv  = (float*)(wpj + (size_t)512*512); // 8*128*8192
  float* pkm  = pkv + (size_t)RSPLIT*128*8192;   // 8*128*128
  float* scinv= pkm + (size_t)RSPLIT*128*128;
  float* pwr  = scinv + 512;
  const size_t need = (size_t)((char*)(pwr + 512) - (char*)d_ws);
  if (ws_size < need) return;

  ushort* XOb = xbf;          // aliases x_bf (dead after qg GEMM)
  ushort* cmb = KQ;           // aliases QS (dead after attn)
  ushort* gbuf = (ushort*)out;// g bf16 in d_out low half (consumed before proj overwrites)

  prep_kernel<<<1, 512, 0, stream>>>(scale_p, power_p, scinv, pwr);
  cvt_x_kernel<<<(int)(MCs/4/256), 256, 0, stream>>>(x, xbf);
  transpose_w_kernel<<<dim3(32,16), 256, 0, stream>>>(qg_w,   wqg, 512, 1024);
  transpose_w_kernel<<<dim3(32,16), 256, 0, stream>>>(kv_w,   wkv, 512, 1024);
  transpose_w_kernel<<<dim3(16,16), 256, 0, stream>>>(proj_w, wpj, 512, 512);

  // kv GEMM: KF features + v bf16
  gemm_bf16_kernel<<<dim3(8, MROWS/128), 256, 0, stream>>>(
      xbf, wkv, 1, scinv, pwr, pos_enc, nullptr, nullptr, KQ, Vb);
  reduce_kv_kernel<<<128*RSPLIT, 256, 0, stream>>>(KQ, Vb, pkv, pkm);
  reduce_final_kernel<<<128, 256, 0, stream>>>(pkv, pkm, Kt);
  // qg GEMM: QS features + g bf16 (into d_out)
  gemm_bf16_kernel<<<dim3(8, MROWS/128), 256, 0, stream>>>(
      xbf, wqg, 0, scinv, pwr, nullptr, nullptr, nullptr, KQ, gbuf);
  attn_mfma_kernel<<<dim3(25, 128), 256, 0, stream>>>(KQ, Kt, XOb);
  conv_combine_kernel<<<dim3(28, 128), 256, 0, stream>>>(Vb, XOb, gbuf, dwc_w, dwc_b, cmb);
  // proj GEMM
  gemm_bf16_kernel<<<dim3(4, MROWS/128), 256, 0, stream>>>(
      cmb, wpj, 2, nullptr, nullptr, nullptr, proj_b, out, nullptr, nullptr);
}

// Round 6
// 933.630 us; speedup vs baseline: 3.6686x; 1.1592x over previous
//
#include <hip/hip_runtime.h>
#include <math.h>

typedef unsigned short ushort;
typedef __attribute__((ext_vector_type(8))) short short8v;
typedef __attribute__((ext_vector_type(4))) short short4v;
typedef __attribute__((ext_vector_type(4))) float float4v;
typedef __attribute__((ext_vector_type(8))) __bf16 bf16x8;

#define NHEADS 8
#define NPOS 3136
#define MROWS 50176          // 16*3136
#define KDIM 512

__device__ __forceinline__ ushort f2bf(float f) {
  union { float f; unsigned u; } x; x.f = f;
  unsigned r = x.u + 0x7fffu + ((x.u >> 16) & 1u);
  return (ushort)(r >> 16);
}
__device__ __forceinline__ float bf2f(ushort h) {
  union { unsigned u; float f; } x; x.u = ((unsigned)h) << 16; return x.f;
}

__device__ __forceinline__ float4v mfma16(short8v a, short8v b, float4v c) {
  return __builtin_amdgcn_mfma_f32_16x16x32_bf16(
      __builtin_bit_cast(bf16x8, a), __builtin_bit_cast(bf16x8, b), c, 0, 0, 0);
}

__device__ __forceinline__ void glds16(const void* g, void* l) {
  __builtin_amdgcn_global_load_lds(
      (const __attribute__((address_space(1))) unsigned int*)g,
      (__attribute__((address_space(3))) unsigned int*)l, 16, 0, 0);
}

// ---------------- prep: scale_inv, power ----------------
__global__ __launch_bounds__(512) void prep_kernel(const float* __restrict__ scale_p,
                                                   const float* __restrict__ power_p,
                                                   float* __restrict__ scinv,
                                                   float* __restrict__ pwr)
{
  int t = threadIdx.x;
  if (t < KDIM) {
    scinv[t] = 1.f / log1pf(expf(scale_p[t]));
    pwr[t]   = 1.f + 4.f / (1.f + expf(-power_p[t]));
  }
}

// ---------------- x fp32 -> bf16 ----------------
__global__ __launch_bounds__(256) void cvt_x_kernel(const float* __restrict__ x,
                                                    ushort* __restrict__ xb)
{
  const size_t i = ((size_t)blockIdx.x * 256 + threadIdx.x) * 4;
  float4v v = *(const float4v*)(x + i);
  short4v o = { (short)f2bf(v[0]), (short)f2bf(v[1]), (short)f2bf(v[2]), (short)f2bf(v[3]) };
  *(short4v*)(xb + i) = o;
}

// ---------------- weight transpose fp32[K][N] -> bf16[N][K] ----------------
__global__ __launch_bounds__(256) void transpose_w_kernel(const float* __restrict__ src,
                                                          ushort* __restrict__ dst,
                                                          int K, int N)
{
  __shared__ float tile[32][33];
  const int t = threadIdx.x, tx = t & 31, ty = t >> 5;
  const int nb = blockIdx.x * 32, kb = blockIdx.y * 32;
  #pragma unroll
  for (int i = 0; i < 4; i++)
    tile[ty + i*8][tx] = src[(size_t)(kb + ty + i*8) * N + nb + tx];
  __syncthreads();
  #pragma unroll
  for (int i = 0; i < 4; i++)
    dst[(size_t)(nb + ty + i*8) * K + kb + tx] = f2bf(tile[tx][ty + i*8]);
}

// ---------------- bf16 MFMA GEMM 128x128xK512, double-buffered ----------------
// A bf16 [M][512]; Bt bf16 [N][512]. C[m][n] = sum_k A[m][k]*Bt[n][k]
// Feature layout (modes 0/1): interleaved f = 2d + (neg?1:0), one u32 store.
// mode 0 (qg): col<512 -> q features into QS; col>=512 -> g bf16 natural (outb1)
// mode 1 (kv): col<512 -> k features (pos_enc+scale); col>=512 -> v bf16 head-major
// mode 2 (proj): outf = d_out natural fp32 + bias
__global__ __launch_bounds__(256) void gemm_bf16_kernel(
    const ushort* __restrict__ A, const ushort* __restrict__ Bt, int mode,
    const float* __restrict__ scinv, const float* __restrict__ pwr,
    const float* __restrict__ pos_enc, const float* __restrict__ bias,
    float* __restrict__ outf, ushort* __restrict__ outb0, ushort* __restrict__ outb1)
{
  __shared__ ushort As[2][128*32];
  __shared__ ushort Bs[2][128*32];
  const int t = threadIdx.x;
  const int wave = t >> 6, lane = t & 63;
  const int m0 = blockIdx.y * 128, n0 = blockIdx.x * 128;
  const int wm = wave >> 1, wn = wave & 1;
  const int rA = lane >> 2;            // row within 16-row staging group
  const int kc = (lane & 3) * 8;       // k-offset (shorts)
  const int ra0 = wave*32, ra1 = wave*32 + 16;

  float4v acc[4][4];
  #pragma unroll
  for (int i = 0; i < 4; i++)
    #pragma unroll
    for (int j = 0; j < 4; j++) { float4v z = {0.f,0.f,0.f,0.f}; acc[i][j] = z; }

  // prologue: stage k0=0 into buffer 0
  glds16(A  + (size_t)(m0 + ra0 + rA)*KDIM + kc, &As[0][ra0*32]);
  glds16(Bt + (size_t)(n0 + ra0 + rA)*KDIM + kc, &Bs[0][ra0*32]);
  glds16(A  + (size_t)(m0 + ra1 + rA)*KDIM + kc, &As[0][ra1*32]);
  glds16(Bt + (size_t)(n0 + ra1 + rA)*KDIM + kc, &Bs[0][ra1*32]);
  __syncthreads();   // compiler inserts vmcnt(0) drain here

  const int lm = lane & 15, q8 = (lane >> 4) * 8;

  for (int k0 = 0; k0 < KDIM; k0 += 32) {
    const int cur = (k0 >> 5) & 1;
    if (k0 + 32 < KDIM) {
      const int nxt = cur ^ 1;
      const int kn = k0 + 32;
      glds16(A  + (size_t)(m0 + ra0 + rA)*KDIM + kn + kc, &As[nxt][ra0*32]);
      glds16(Bt + (size_t)(n0 + ra0 + rA)*KDIM + kn + kc, &Bs[nxt][ra0*32]);
      glds16(A  + (size_t)(m0 + ra1 + rA)*KDIM + kn + kc, &As[nxt][ra1*32]);
      glds16(Bt + (size_t)(n0 + ra1 + rA)*KDIM + kn + kc, &Bs[nxt][ra1*32]);
    }
    const ushort* Asc = As[cur];
    const ushort* Bsc = Bs[cur];
    short8v a[4], b[4];
    #pragma unroll
    for (int i = 0; i < 4; i++) {
      a[i] = *(const short8v*)&Asc[(wm*64 + i*16 + lm)*32 + q8];
      b[i] = *(const short8v*)&Bsc[(wn*64 + i*16 + lm)*32 + q8];
    }
    #pragma unroll
    for (int i = 0; i < 4; i++)
      #pragma unroll
      for (int j = 0; j < 4; j++)
        acc[i][j] = mfma16(a[i], b[j], acc[i][j]);
    __syncthreads();   // drains next-iter prefetch after the MFMA burst
  }

  const int rq = (lane >> 4) * 4;
  #pragma unroll
  for (int i = 0; i < 4; i++) {
    #pragma unroll
    for (int r = 0; r < 4; r++) {
      const int grow = m0 + wm*64 + i*16 + rq + r;
      const int bb = grow / NPOS;
      const int nn = grow - bb * NPOS;
      #pragma unroll
      for (int j = 0; j < 4; j++) {
        const int gcol = n0 + wn*64 + j*16 + lm;
        const float val = acc[i][j][r];
        if (mode == 2) {
          outf[(size_t)grow * 512 + gcol] = val + bias[gcol];
        } else if (gcol < 512) {
          float sv;
          if (mode == 0) sv = val * scinv[gcol];
          else           sv = (val + pos_enc[(size_t)nn*512 + gcol]) * scinv[gcol];
          const float p = pwr[gcol];
          const float aq = fabsf(sv);
          float f = 0.f;
          if (aq > 0.f) f = exp2f(p * log2f(aq));
          const unsigned fb = (unsigned)f2bf(f);
          unsigned pack = 0;
          if (sv > 0.f)      pack = fb;
          else if (sv < 0.f) pack = fb << 16;
          const int h = gcol >> 6, d = gcol & 63;
          unsigned* qrow = (unsigned*)(outb0 + (((size_t)((bb << 3) + h) * NPOS + nn) << 7));
          qrow[d] = pack;   // features interleaved: f=2d (pos), 2d+1 (neg)
        } else {
          const int c2 = gcol - 512;
          if (mode == 0) {
            outb1[(size_t)grow * 512 + c2] = f2bf(val);        // g bf16 natural
          } else {
            const int h = c2 >> 6, d = c2 & 63;
            outb1[(((size_t)((bb << 3) + h) * NPOS + nn) << 6) + d] = f2bf(val);
          }
        }
      }
    }
  }
}

// ---------------- kf outer-product partial reduction ----------------
// (feature axis is in interleaved order now; this kernel is order-agnostic)
#define RSPLIT 8
#define RCHUNK 392
__global__ __launch_bounds__(256) void reduce_kv_kernel(
    const ushort* __restrict__ KF, const ushort* __restrict__ Vb,
    float* __restrict__ pkv, float* __restrict__ pkm)
{
  const int bh = blockIdx.x >> 3, s = blockIdx.x & 7;
  const int t = threadIdx.x;
  __shared__ ushort kf_s[8*128];
  __shared__ ushort v_s[8*64];
  const int td = t & 31, te = t >> 5;
  const int d4 = td * 4, e8 = te * 8;
  float acc[4][8];
  #pragma unroll
  for (int c = 0; c < 4; c++)
    #pragma unroll
    for (int e = 0; e < 8; e++) acc[c][e] = 0.f;
  float km4[4] = {0.f,0.f,0.f,0.f};
  const int nbase = s * RCHUNK;

  for (int g = 0; g < RCHUNK/8; g++) {
    const int n = nbase + g*8;
    *(short4v*)&kf_s[(t>>5)*128 + (t&31)*4] =
        *(const short4v*)&KF[(((size_t)bh*NPOS + n + (t>>5)) << 7) + (t&31)*4];
    if (t < 128)
      *(short4v*)&v_s[(t>>4)*64 + (t&15)*4] =
          *(const short4v*)&Vb[(((size_t)bh*NPOS + n + (t>>4)) << 6) + (t&15)*4];
    __syncthreads();
    #pragma unroll
    for (int i = 0; i < 8; i++) {
      short4v k4 = *(const short4v*)&kf_s[i*128 + d4];
      short8v v8 = *(const short8v*)&v_s[i*64 + e8];
      float kf4[4], vf[8];
      #pragma unroll
      for (int c = 0; c < 4; c++) kf4[c] = bf2f((ushort)k4[c]);
      #pragma unroll
      for (int e = 0; e < 8; e++) vf[e] = bf2f((ushort)v8[e]);
      if (te == 0) {
        #pragma unroll
        for (int c = 0; c < 4; c++) km4[c] += kf4[c];
      }
      #pragma unroll
      for (int c = 0; c < 4; c++)
        #pragma unroll
        for (int e = 0; e < 8; e++) acc[c][e] = fmaf(kf4[c], vf[e], acc[c][e]);
    }
    __syncthreads();
  }
  float* op = pkv + ((size_t)(s*128 + bh) << 13);
  #pragma unroll
  for (int c = 0; c < 4; c++) {
    float4v o0 = {acc[c][0], acc[c][1], acc[c][2], acc[c][3]};
    float4v o1 = {acc[c][4], acc[c][5], acc[c][6], acc[c][7]};
    *(float4v*)&op[(d4+c)*64 + e8]     = o0;
    *(float4v*)&op[(d4+c)*64 + e8 + 4] = o1;
  }
  if (te == 0) {
    #pragma unroll
    for (int c = 0; c < 4; c++) pkm[((size_t)(s*128 + bh) << 7) + d4 + c] = km4[c];
  }
}

// ---------------- final reduce -> kvf2^T bf16 [bh][80][128] ----------------
// interleaved feature space: opp-branch swap is f ^ 1 (pos<->neg adjacent pair)
__global__ __launch_bounds__(256) void reduce_final_kernel(
    const float* __restrict__ pkv, const float* __restrict__ pkm,
    ushort* __restrict__ Kt)
{
  const int bh = blockIdx.x, t = threadIdx.x;
  const float inv_n = 1.f / (float)NPOS;
  for (int i = t; i < 8192; i += 256) {
    float s = 0.f;
    #pragma unroll
    for (int sp = 0; sp < RSPLIT; sp++) s += pkv[((size_t)(sp*128 + bh) << 13) + i];
    const int d = i >> 6, e = i & 63;
    const int dd = (e < 32) ? d : (d ^ 1);
    Kt[((size_t)bh*80 + e)*128 + dd] = f2bf(s * inv_n);
  }
  if (t < 128) {
    float s = 0.f;
    #pragma unroll
    for (int sp = 0; sp < RSPLIT; sp++) s += pkm[((size_t)(sp*128 + bh) << 7) + t];
    const ushort b = f2bf(s * inv_n);
    Kt[((size_t)bh*80 + 64)*128 + t] = b;          // km (denom_sim column)
    Kt[((size_t)bh*80 + 65)*128 + (t ^ 1)] = b;    // km swapped (denom_opp)
  }
  for (int i = t; i < 14*128; i += 256) Kt[((size_t)bh*80 + 66)*128 + i] = 0;
}

// ---------------- attention apply: MFMA [128x80] = QS[128x128] @ Kt^T -------
__global__ __launch_bounds__(256) void attn_mfma_kernel(
    const ushort* __restrict__ QS, const ushort* __restrict__ Kt,
    ushort* __restrict__ XO)
{
  __shared__ ushort qs_s[128*128];
  __shared__ ushort kv_s[80*128];
  const int t = threadIdx.x, wave = t >> 6, lane = t & 63;
  const int bh = blockIdx.y;
  const int n0 = blockIdx.x * 128;

  const ushort* ksrc = Kt + (size_t)bh * 80 * 128;
  #pragma unroll
  for (int j = 0; j < 5; j++) {
    const int elem = (j*4096 + wave*1024) >> 1;
    glds16(ksrc + elem + lane*8, kv_s + elem);
  }
  const ushort* qsrc = QS + ((size_t)bh * NPOS + n0) * 128;
  #pragma unroll
  for (int j = 0; j < 8; j++) {
    const int elem = (j*4096 + wave*1024) >> 1;
    glds16(qsrc + elem + lane*8, qs_s + elem);
  }
  __syncthreads();

  const int lm = lane & 15, q8 = (lane >> 4) * 8;
  float4v acc[2][5];
  #pragma unroll
  for (int i = 0; i < 2; i++)
    #pragma unroll
    for (int j = 0; j < 5; j++) { float4v z = {0.f,0.f,0.f,0.f}; acc[i][j] = z; }

  #pragma unroll
  for (int ks = 0; ks < 4; ks++) {
    short8v a[2], b[5];
    #pragma unroll
    for (int i = 0; i < 2; i++)
      a[i] = *(const short8v*)&qs_s[(wave*32 + i*16 + lm)*128 + ks*32 + q8];
    #pragma unroll
    for (int j = 0; j < 5; j++)
      b[j] = *(const short8v*)&kv_s[(j*16 + lm)*128 + ks*32 + q8];
    #pragma unroll
    for (int i = 0; i < 2; i++)
      #pragma unroll
      for (int j = 0; j < 5; j++)
        acc[i][j] = mfma16(a[i], b[j], acc[i][j]);
  }

  const int rq = (lane >> 4) * 4;
  #pragma unroll
  for (int i = 0; i < 2; i++) {
    #pragma unroll
    for (int r = 0; r < 4; r++) {
      const int n = n0 + wave*32 + i*16 + rq + r;
      const float dsim = __shfl(acc[i][4][r], lane & 48);
      const float dopp = __shfl(acc[i][4][r], (lane & 48) | 1);
      const float zs = 1.f / (dsim + 1e-6f);
      const float zo = 1.f / (dopp + 1e-6f);
      if (n < NPOS) {
        ushort* orow = XO + (((size_t)bh * NPOS + n) << 6);
        #pragma unroll
        for (int j = 0; j < 4; j++)
          orow[j*16 + lm] = f2bf(acc[i][j][r] * ((j < 2) ? zs : zo));
      }
    }
  }
}

// ------- 5x5 depthwise conv + (xo+vd)*g -> combined bf16 natural -------
__global__ __launch_bounds__(256) void conv_combine_kernel(
    const ushort* __restrict__ Vb, const ushort* __restrict__ XO,
    const ushort* __restrict__ g, const float* __restrict__ dwc_w,
    const float* __restrict__ dwc_b, ushort* __restrict__ cmb)
{
  __shared__ ushort vs[6*60*64];   // 46080 B -> 3 blocks/CU
  const int t = threadIdx.x;
  const int bh = blockIdx.y, b = bh >> 3, h = bh & 7;
  const int y0 = blockIdx.x * 2;
  for (int i = t; i < 5760; i += 256) {
    const int ry = i / 960;
    const int rem = i - ry * 960;
    const int xx = (rem >> 4) - 2;
    const int c4 = (rem & 15) * 4;
    const int yy = y0 - 2 + ry;
    short4v val = {0,0,0,0};
    if (yy >= 0 && yy < 56 && xx >= 0 && xx < 56)
      val = *(const short4v*)&Vb[(((size_t)bh*NPOS + yy*56 + xx) << 6) + c4];
    *(short4v*)&vs[ry*3840 + (rem >> 4)*64 + c4] = val;
  }
  __syncthreads();

  const int c = t & 63, xg = t >> 6;   // 4 x-groups of 14
  float w[25];
  #pragma unroll
  for (int i = 0; i < 25; i++) w[i] = dwc_w[c*25 + i];
  const float bias = dwc_b[c];

  #pragma unroll
  for (int y = 0; y < 2; y++) {
    float acc[14];
    #pragma unroll
    for (int xi = 0; xi < 14; xi++) acc[xi] = bias;
    #pragma unroll
    for (int ky = 0; ky < 5; ky++) {
      const ushort* row = &vs[(y + ky)*3840 + (xg*14)*64 + c];
      #pragma unroll
      for (int xl = 0; xl < 18; xl++) {
        const float val = bf2f(row[xl*64]);
        #pragma unroll
        for (int kx = 0; kx < 5; kx++) {
          const int xi = xl - kx;
          if (xi >= 0 && xi < 14)
            acc[xi] = fmaf(w[ky*5 + kx], val, acc[xi]);
        }
      }
    }
    const int yo = y0 + y;
    #pragma unroll
    for (int xi = 0; xi < 14; xi++) {
      const int n = yo*56 + xg*14 + xi;
      const float xov = bf2f(XO[(((size_t)bh*NPOS + n) << 6) + c]);
      const size_t nat = ((size_t)b*NPOS + n)*512 + h*64 + c;
      cmb[nat] = f2bf((xov + acc[xi]) * bf2f(g[nat]));
    }
  }
}

// ---------------- launch ----------------
extern "C" void kernel_launch(void* const* d_in, const int* in_sizes, int n_in,
                              void* d_out, int out_size, void* d_ws, size_t ws_size,
                              hipStream_t stream)
{
  const float* x       = (const float*)d_in[0];
  const float* qg_w    = (const float*)d_in[1];
  const float* kv_w    = (const float*)d_in[2];
  const float* proj_w  = (const float*)d_in[3];
  const float* proj_b  = (const float*)d_in[4];
  const float* pos_enc = (const float*)d_in[5];
  const float* scale_p = (const float*)d_in[6];
  const float* power_p = (const float*)d_in[7];
  const float* dwc_w   = (const float*)d_in[8];
  const float* dwc_b   = (const float*)d_in[9];
  float* out = (float*)d_out;

  const size_t MCs = (size_t)MROWS * 512;        // 25,690,112
  ushort* xbf = (ushort*)d_ws;                   // x bf16 -> later XO bf16 head-major
  ushort* KQ  = xbf + MCs;                       // KF -> QS [128][3136][128] -> later cmb
  ushort* Vb  = KQ + 2*MCs + 8192;               // v bf16 head-major
  ushort* Kt  = Vb + MCs;                        // kvf2^T bf16 [128][80][128]
  ushort* wqg = Kt + (size_t)128*80*128;         // qg_w^T bf16 [1024][512]
  ushort* wkv = wqg + (size_t)1024*512;
  ushort* wpj = wkv + (size_t)1024*512;          // proj_w^T bf16 [512][512]
  float* pkv  = (float*)(wpj + (size_t)512*512); // 8*128*8192
  float* pkm  = pkv + (size_t)RSPLIT*128*8192;   // 8*128*128
  float* scinv= pkm + (size_t)RSPLIT*128*128;
  float* pwr  = scinv + 512;
  const size_t need = (size_t)((char*)(pwr + 512) - (char*)d_ws);
  if (ws_size < need) return;

  ushort* XOb = xbf;          // aliases x_bf (dead after qg GEMM)
  ushort* cmb = KQ;           // aliases QS (dead after attn)
  ushort* gbuf = (ushort*)out;// g bf16 in d_out low half (consumed before proj overwrites)

  prep_kernel<<<1, 512, 0, stream>>>(scale_p, power_p, scinv, pwr);
  cvt_x_kernel<<<(int)(MCs/4/256), 256, 0, stream>>>(x, xbf);
  transpose_w_kernel<<<dim3(32,16), 256, 0, stream>>>(qg_w,   wqg, 512, 1024);
  transpose_w_kernel<<<dim3(32,16), 256, 0, stream>>>(kv_w,   wkv, 512, 1024);
  transpose_w_kernel<<<dim3(16,16), 256, 0, stream>>>(proj_w, wpj, 512, 512);

  // kv GEMM: KF features + v bf16
  gemm_bf16_kernel<<<dim3(8, MROWS/128), 256, 0, stream>>>(
      xbf, wkv, 1, scinv, pwr, pos_enc, nullptr, nullptr, KQ, Vb);
  reduce_kv_kernel<<<128*RSPLIT, 256, 0, stream>>>(KQ, Vb, pkv, pkm);
  reduce_final_kernel<<<128, 256, 0, stream>>>(pkv, pkm, Kt);
  // qg GEMM: QS features + g bf16 (into d_out)
  gemm_bf16_kernel<<<dim3(8, MROWS/128), 256, 0, stream>>>(
      xbf, wqg, 0, scinv, pwr, nullptr, nullptr, nullptr, KQ, gbuf);
  attn_mfma_kernel<<<dim3(25, 128), 256, 0, stream>>>(KQ, Kt, XOb);
  conv_combine_kernel<<<dim3(28, 128), 256, 0, stream>>>(Vb, XOb, gbuf, dwc_w, dwc_b, cmb);
  // proj GEMM
  gemm_bf16_kernel<<<dim3(4, MROWS/128), 256, 0, stream>>>(
      cmb, wpj, 2, nullptr, nullptr, nullptr, proj_b, out, nullptr, nullptr);
}